// Round 21
// baseline (70.794 us; speedup 1.0000x reference)
//
#include <hip/hip_runtime.h>

// ScaledDotProductAttention: causal cosine attention.
// B=4 H=16 N=2048 D=64, fp32 in/out, bf16 MFMA compute.
//
// Round 21 = r20 (best, 70.29us) + two conservative changes:
//  (1) 3-deep LDS buffers (48 KB) with barrier-THEN-issue ordering:
//      vmcnt(2) -> s_barrier -> issue stage(kt+2) -> compute(kt).
//      barrier(kt) retires compute(kt-1) in all waves BEFORE stage(kt+2)
//      overwrites buf[(kt-1)%3]; vmcnt(2) pre-barrier publishes stage(kt).
//      48 KB/block -> 3 blocks/CU can co-reside (144 <= 160 KB) -> tail
//      smoothing of the heavy-first imbalance.
//  (2) in-place softmax on sacc (no pv[32] copy).
//  - structure: QBLK=256 (8 waves x 32 q-rows), KVBLK=64, grid 512,
//    heavy-first map, 1 barrier/tile, counted vmcnt (2/0), gload_lds(16B).
//  - deferred lsum (vector accumulate, tree once in epilogue).
//  - fused prep; Kn/Vt pre-swizzled (elem ^= (row&7)<<3 per 64x64 tile).
//  - no-max softmax: scores cosine-bounded (|s| <= g*log2e ~31.7) ->
//    p = exp2(s) directly, exact by shift-invariance.
//  - swapped-operand MFMA, cvt_pk + permlane32_swap P repack.

#define BATCH 4
#define HEADS 16
#define SEQ   2048
#define DIM   64
#define EPS   1e-8f
#define LOG2E 1.44269504088896340736f

typedef short bf16x8 __attribute__((ext_vector_type(8)));
typedef short s16x4  __attribute__((ext_vector_type(4)));
typedef float fx16   __attribute__((ext_vector_type(16)));
typedef unsigned int u32x4 __attribute__((ext_vector_type(4)));

static __device__ __forceinline__ short f2bf(float x) {
    unsigned u = __float_as_uint(x);
    unsigned r = (u + 0x7fffu + ((u >> 16) & 1u)) >> 16;   // RNE
    return (short)r;
}
static __device__ __forceinline__ unsigned cvt_pk(float lo, float hi) {
    unsigned r;
    asm("v_cvt_pk_bf16_f32 %0, %1, %2" : "=v"(r) : "v"(lo), "v"(hi));
    return r;
}
static __device__ __forceinline__ void gload_lds16(const short* g, short* l) {
    __builtin_amdgcn_global_load_lds(
        (const __attribute__((address_space(1))) void*)g,
        (__attribute__((address_space(3))) void*)l, 16, 0, 0);
}

// ---------------------------------------------------------------------------
// Fused prep: per (64-row tile nt, bh):
//   Kn[bh][nt][r][e ^ ((r&7)<<3)] = bf16(K_hat[bh][nt*64+r][e])
//   Vt[bh][nt][d][k ^ ((d&7)<<3)] = bf16(V[bh][nt*64+k][d])
// ---------------------------------------------------------------------------
#define TLDS 68

__global__ __launch_bounds__(256) void prep_kv(
    const float* __restrict__ K, const float* __restrict__ V,
    short* __restrict__ Kn, short* __restrict__ Vt)
{
    const int nt = blockIdx.x;
    const int bh = blockIdx.y;
    const int tid = threadIdx.x;

    const float* Kb = K + ((size_t)bh * SEQ + (size_t)nt * 64) * DIM;
    short* Kno = Kn + ((size_t)bh << 17) + (nt << 12);
    const int c4 = (tid & 15) * 4;
#pragma unroll
    for (int i = 0; i < 4; ++i) {
        const int r = i * 16 + (tid >> 4);
        float4 v = *(const float4*)(Kb + (size_t)r * DIM + c4);
        float ss = v.x * v.x + v.y * v.y + v.z * v.z + v.w * v.w;
        ss += __shfl_xor(ss, 1);
        ss += __shfl_xor(ss, 2);
        ss += __shfl_xor(ss, 4);
        ss += __shfl_xor(ss, 8);
        float s = 1.0f / (sqrtf(ss) + EPS);
        s16x4 o;
        o[0] = f2bf(v.x * s);
        o[1] = f2bf(v.y * s);
        o[2] = f2bf(v.z * s);
        o[3] = f2bf(v.w * s);
        *(s16x4*)(Kno + (r << 6) + (c4 ^ ((r & 7) << 3))) = o;
    }

    const float* Vb = V + ((size_t)bh * SEQ + (size_t)nt * 64) * DIM;
    short* Vo = Vt + ((size_t)bh << 17) + (nt << 12);
    __shared__ short lds[DIM * TLDS];
    const int cg = tid & 15;
    const int rr = tid >> 4;
#pragma unroll
    for (int i = 0; i < 4; ++i) {
        int n  = rr + i * 16;
        int d0 = cg * 4;
        float4 v = *(const float4*)(Vb + (size_t)n * DIM + d0);
        lds[(d0 + 0) * TLDS + n] = f2bf(v.x);
        lds[(d0 + 1) * TLDS + n] = f2bf(v.y);
        lds[(d0 + 2) * TLDS + n] = f2bf(v.z);
        lds[(d0 + 3) * TLDS + n] = f2bf(v.w);
    }
    __syncthreads();
#pragma unroll
    for (int i = 0; i < 4; ++i) {
        int d  = rr + i * 16;
        int nl = cg * 4;
        s16x4 o;
        o[0] = lds[d * TLDS + nl + 0];
        o[1] = lds[d * TLDS + nl + 1];
        o[2] = lds[d * TLDS + nl + 2];
        o[3] = lds[d * TLDS + nl + 3];
        *(s16x4*)(Vo + (d << 6) + (nl ^ ((d & 7) << 3))) = o;
    }
}

// ---------------------------------------------------------------------------
// Flash attention. 512 threads = 8 waves, QBLK=256, KVBLK=64.
// Grid 512, heavy-first; 48 KB LDS -> up to 3 blocks/CU. 3-deep buffers,
// ONE s_barrier per tile; order: vmcnt -> barrier -> issue stage(kt+2).
//
// mfma_f32_32x32x16_bf16 layouts:
//   A: row = lane&31, k = (lane>>5)*8 + j
//   B: col = lane&31, k = (lane>>5)*8 + j
//   C/D: col = lane&31, row = (reg&3) + 8*(reg>>2) + 4*(lane>>5)
// ---------------------------------------------------------------------------
__global__ __launch_bounds__(512) void attn_fwd(
    const float* __restrict__ Q, const float* __restrict__ scale,
    const short* __restrict__ Kn, const short* __restrict__ Vt,
    float* __restrict__ out)
{
    const int lid = blockIdx.x;                       // 0..511
    const int bh  = (lid & 7) * 8 + ((lid >> 3) & 7); // XCD lid%8 owns bh/8
    const int qb  = 7 - (lid >> 6);                   // heavy q-blocks first
    const int tid = threadIdx.x;
    const int w   = tid >> 6;                         // wave 0..7
    const int l   = tid & 63;
    const int lq  = l & 31;
    const int hi  = l >> 5;

    const short* Kb = Kn + ((size_t)bh << 17);
    const short* Vb = Vt + ((size_t)bh << 17);
    const float  g  = scale[bh & (HEADS - 1)];

    __shared__ __align__(16) short ldsK[3][64 * 64];
    __shared__ __align__(16) short ldsV[3][64 * 64];

    const int toff = tid * 8;   // 512 thr x 8 shorts = full 4096-short tile

    const int wlo  = qb * 256 + w * 32;   // wave's first q-row
    const int whi  = wlo + 31;
    const int qrow = wlo + lq;
    const int nkt  = 4 * qb + 4;

    // ---- prologue: stage tiles 0 and 1 ----
    gload_lds16(Kb + toff,        &ldsK[0][toff]);
    gload_lds16(Vb + toff,        &ldsV[0][toff]);
    gload_lds16(Kb + 4096 + toff, &ldsK[1][toff]);
    gload_lds16(Vb + 4096 + toff, &ldsV[1][toff]);

    // ---- fused Q-norm (overlaps stage latency; its use drains vmcnt once
    //      here, before the steady loop -> stages 0,1 also landed) ----
    const float* Qrow = Q + ((size_t)bh * SEQ + qrow) * DIM;
    float qv[4][8];
    float ss = 0.f;
#pragma unroll
    for (int c = 0; c < 4; ++c) {
        float4 a = *(const float4*)(Qrow + c * 16 + hi * 8);
        float4 b = *(const float4*)(Qrow + c * 16 + hi * 8 + 4);
        qv[c][0] = a.x; qv[c][1] = a.y; qv[c][2] = a.z; qv[c][3] = a.w;
        qv[c][4] = b.x; qv[c][5] = b.y; qv[c][6] = b.z; qv[c][7] = b.w;
#pragma unroll
        for (int jj = 0; jj < 8; ++jj) ss += qv[c][jj] * qv[c][jj];
    }
    ss += __shfl_xor(ss, 32);
    const float sc = g * LOG2E / (sqrtf(ss) + EPS);

    bf16x8 qbf[4];
#pragma unroll
    for (int c = 0; c < 4; ++c) {
        u32x4 wds;
#pragma unroll
        for (int m = 0; m < 4; ++m)
            wds[m] = cvt_pk(qv[c][2 * m] * sc, qv[c][2 * m + 1] * sc);
        qbf[c] = __builtin_bit_cast(bf16x8, wds);
    }

    fx16 oacc[2];
    fx16 lacc;                       // deferred lsum partials
#pragma unroll
    for (int dt = 0; dt < 2; ++dt)
#pragma unroll
        for (int r = 0; r < 16; ++r) oacc[dt][r] = 0.f;
#pragma unroll
    for (int r = 0; r < 16; ++r) lacc[r] = 0.f;

    int cur = 0;   // kt % 3
    for (int kt = 0; kt < nkt; ++kt) {
        // wait own stage(kt) landed (only stage(kt+1) may stay in flight),
        // then barrier: publishes all waves' stage(kt) AND retires
        // compute(kt-1) so stage(kt+2) may overwrite buf[(kt-1)%3].
        if (kt + 1 < nkt) {
            asm volatile("s_waitcnt vmcnt(2)" ::: "memory");
        } else {
            asm volatile("s_waitcnt vmcnt(0)" ::: "memory");
        }
        __builtin_amdgcn_s_barrier();

        if (kt + 2 < nkt) {
            int nb = cur + 2; if (nb >= 3) nb -= 3;
            const short* gK = Kb + (size_t)(kt + 2) * 4096;
            const short* gV = Vb + (size_t)(kt + 2) * 4096;
            gload_lds16(gK + toff, &ldsK[nb][toff]);
            gload_lds16(gV + toff, &ldsV[nb][toff]);
        }

        const int k0 = kt * 64;
        if (k0 <= whi) {   // wave-uniform causal skip (barrier outside)
            const short* lk = ldsK[cur];
            const short* lv = ldsV[cur];

            // ---- K frags from LDS (swizzled), S' = K x Q^T ----
            fx16 sacc[2];
#pragma unroll
            for (int t = 0; t < 2; ++t)
#pragma unroll
                for (int r = 0; r < 16; ++r) sacc[t][r] = 0.f;

            bf16x8 kf[2][4];
#pragma unroll
            for (int t = 0; t < 2; ++t)
#pragma unroll
                for (int c = 0; c < 4; ++c) {
                    int r = t * 32 + lq;
                    kf[t][c] = *(const bf16x8*)
                        &lk[(r << 6) + ((c * 16 + hi * 8) ^ ((r & 7) << 3))];
                }
            __builtin_amdgcn_s_setprio(1);
#pragma unroll
            for (int c = 0; c < 4; ++c) {
                sacc[0] = __builtin_amdgcn_mfma_f32_32x32x16_bf16(kf[0][c], qbf[c], sacc[0], 0, 0, 0);
                sacc[1] = __builtin_amdgcn_mfma_f32_32x32x16_bf16(kf[1][c], qbf[c], sacc[1], 0, 0, 0);
            }
            __builtin_amdgcn_s_setprio(0);

            // ---- V frags from LDS (latency hides under softmax) ----
            bf16x8 vf[2][4];
#pragma unroll
            for (int dt = 0; dt < 2; ++dt)
#pragma unroll
                for (int ks = 0; ks < 4; ++ks) {
                    int d = dt * 32 + lq;
                    vf[dt][ks] = *(const bf16x8*)
                        &lv[(d << 6) + ((ks * 16 + hi * 8) ^ ((d & 7) << 3))];
                }

            // ---- causal mask (in place): only the wave's diagonal tile ----
            if (k0 + 63 > wlo) {
#pragma unroll
                for (int t = 0; t < 2; ++t)
#pragma unroll
                    for (int r = 0; r < 16; ++r) {
                        int key = k0 + 32 * t + (r & 3) + 8 * (r >> 2) + 4 * hi;
                        if (key > qrow) sacc[t][r] = -3.0e38f;
                    }
            }

            // ---- p = exp2(s) in place (cosine-bounded, no max shift) ----
#pragma unroll
            for (int t = 0; t < 2; ++t)
#pragma unroll
                for (int r = 0; r < 16; ++r)
                    sacc[t][r] = __builtin_amdgcn_exp2f(sacc[t][r]);

            // ---- deferred lsum: vector accumulate only ----
#pragma unroll
            for (int r = 0; r < 16; ++r)
                lacc[r] += sacc[0][r] + sacc[1][r];

            // ---- repack P -> B-fragments via v_permlane32_swap_b32 ----
            u32x4 paw[4];
#pragma unroll
            for (int ks = 0; ks < 4; ++ks) {
                const int t = ks >> 1;
                const int b0 = (ks & 1) * 8;
#pragma unroll
                for (int m = 0; m < 2; ++m) {
                    unsigned a = cvt_pk(sacc[t][b0 + 2 * m], sacc[t][b0 + 2 * m + 1]);
                    unsigned b = cvt_pk(sacc[t][b0 + 2 * m + 4], sacc[t][b0 + 2 * m + 5]);
                    asm("v_permlane32_swap_b32 %0, %1" : "+v"(a), "+v"(b));
                    paw[ks][m]     = a;
                    paw[ks][m + 2] = b;
                }
            }

            // ---- O' += Vt x P ----
            __builtin_amdgcn_s_setprio(1);
#pragma unroll
            for (int dt = 0; dt < 2; ++dt)
#pragma unroll
                for (int ks = 0; ks < 4; ++ks) {
                    bf16x8 pa = __builtin_bit_cast(bf16x8, paw[ks]);
                    oacc[dt] = __builtin_amdgcn_mfma_f32_32x32x16_bf16(vf[dt][ks], pa, oacc[dt], 0, 0, 0);
                }
            __builtin_amdgcn_s_setprio(0);
        }
        cur = (cur == 2) ? 0 : cur + 1;
    }

    // ---- epilogue: finish lsum reduction, then out[q][d] = O'/lsum ----
    float ts[8];
#pragma unroll
    for (int r = 0; r < 8; ++r) ts[r] = lacc[r] + lacc[r + 8];
#pragma unroll
    for (int r = 0; r < 4; ++r) ts[r] += ts[r + 4];
    float lsum = (ts[0] + ts[1]) + (ts[2] + ts[3]);
    lsum += __shfl_xor(lsum, 32);

    float inv = 1.0f / lsum;
    size_t rb = ((size_t)bh * SEQ + (size_t)qrow) * DIM;
#pragma unroll
    for (int dt = 0; dt < 2; ++dt)
#pragma unroll
        for (int g4 = 0; g4 < 4; ++g4) {
            float4 o4;
            o4.x = oacc[dt][4 * g4 + 0] * inv;
            o4.y = oacc[dt][4 * g4 + 1] * inv;
            o4.z = oacc[dt][4 * g4 + 2] * inv;
            o4.w = oacc[dt][4 * g4 + 3] * inv;
            *(float4*)(out + rb + dt * 32 + 8 * g4 + 4 * hi) = o4;
        }
}

// ---------------------------------------------------------------------------
extern "C" void kernel_launch(void* const* d_in, const int* in_sizes, int n_in,
                              void* d_out, int out_size, void* d_ws, size_t ws_size,
                              hipStream_t stream)
{
    const float* Q  = (const float*)d_in[0];
    const float* K  = (const float*)d_in[1];
    const float* V  = (const float*)d_in[2];
    const float* qs = (const float*)d_in[3];
    float* out = (float*)d_out;

    const size_t nElem = (size_t)BATCH * HEADS * SEQ * DIM;
    short* Kn = (short*)d_ws;
    short* Vt = Kn + nElem;

    {
        dim3 grid(SEQ / 64, BATCH * HEADS);
        prep_kv<<<grid, 256, 0, stream>>>(K, V, Kn, Vt);
    }
    {
        // 512 blocks: XCD lid%8 owns bh chunk; 8 q-blocks per bh
        attn_fwd<<<(SEQ / 256) * BATCH * HEADS, 512, 0, stream>>>(Q, qs, Kn, Vt, out);
    }
}

// Round 22
// 70.132 us; speedup vs baseline: 1.0094x; 1.0094x over previous
//
#include <hip/hip_runtime.h>

// ScaledDotProductAttention: causal cosine attention.
// B=4 H=16 N=2048 D=64, fp32 in/out, bf16 MFMA compute.
//
// FINAL (= round 20, best measured: 70.29us total / 66.9us attn).
// Converged configuration after 21 rounds of counter-driven search:
//  - QBLK=256 (8 waves x 32 q-rows), KVBLK=64, grid 512 = 2 blocks/CU,
//    heavy-first map (balanced maps tested 2x, both worse: block placement
//    is not source-steerable).
//  - 4-deep LDS buffers, ONE s_barrier per tile (vmcnt-before-barrier),
//    counted vmcnt (4/2/0), global_load_lds(16B) staged 2 tiles ahead.
//  - no-max softmax: cosine-bounded scores (|s| <= g*log2e ~31.7) ->
//    p = exp2(s) directly, exact by softmax shift-invariance. Removes the
//    running max, rescale, and per-tile max-reduce entirely.
//  - deferred lsum: per-tile vector accumulate, tree+shfl once in epilogue
//    (overflow-safe: p <= 2^31.7, sum <= 7e12 << f32 max).
//  - swapped-operand MFMA (S' = K x Q^T): per-lane row ownership ->
//    in-register softmax; P->B-frag repack via v_cvt_pk_bf16_f32 +
//    v_permlane32_swap_b32 (no LDS round-trip, no ds_bpermute).
//  - Kn/Vt pre-swizzled (elem ^= (row&7)<<3 per 64x64 tile) -> ds_read_b128
//    at minimum 2-lane/bank aliasing; fused prep kernel (K-norm+V-transpose).
// Structural plateau: no pipe >30% (MFMA 20%, VALU 28%, HBM 14%); wall is
// the intra-wave serial chain x worst-CU work. 3 pipelining attempts and
// 14 structural variants all regressed vs this configuration.

#define BATCH 4
#define HEADS 16
#define SEQ   2048
#define DIM   64
#define EPS   1e-8f
#define LOG2E 1.44269504088896340736f

typedef short bf16x8 __attribute__((ext_vector_type(8)));
typedef short s16x4  __attribute__((ext_vector_type(4)));
typedef float fx16   __attribute__((ext_vector_type(16)));
typedef unsigned int u32x4 __attribute__((ext_vector_type(4)));

static __device__ __forceinline__ short f2bf(float x) {
    unsigned u = __float_as_uint(x);
    unsigned r = (u + 0x7fffu + ((u >> 16) & 1u)) >> 16;   // RNE
    return (short)r;
}
static __device__ __forceinline__ unsigned cvt_pk(float lo, float hi) {
    unsigned r;
    asm("v_cvt_pk_bf16_f32 %0, %1, %2" : "=v"(r) : "v"(lo), "v"(hi));
    return r;
}
static __device__ __forceinline__ void gload_lds16(const short* g, short* l) {
    __builtin_amdgcn_global_load_lds(
        (const __attribute__((address_space(1))) void*)g,
        (__attribute__((address_space(3))) void*)l, 16, 0, 0);
}

// ---------------------------------------------------------------------------
// Fused prep: per (64-row tile nt, bh):
//   Kn[bh][nt][r][e ^ ((r&7)<<3)] = bf16(K_hat[bh][nt*64+r][e])
//   Vt[bh][nt][d][k ^ ((d&7)<<3)] = bf16(V[bh][nt*64+k][d])
// ---------------------------------------------------------------------------
#define TLDS 68

__global__ __launch_bounds__(256) void prep_kv(
    const float* __restrict__ K, const float* __restrict__ V,
    short* __restrict__ Kn, short* __restrict__ Vt)
{
    const int nt = blockIdx.x;
    const int bh = blockIdx.y;
    const int tid = threadIdx.x;

    // ---- K: L2-normalize 64 rows (16-lane group per row, 4 passes) ----
    const float* Kb = K + ((size_t)bh * SEQ + (size_t)nt * 64) * DIM;
    short* Kno = Kn + ((size_t)bh << 17) + (nt << 12);
    const int c4 = (tid & 15) * 4;
#pragma unroll
    for (int i = 0; i < 4; ++i) {
        const int r = i * 16 + (tid >> 4);
        float4 v = *(const float4*)(Kb + (size_t)r * DIM + c4);
        float ss = v.x * v.x + v.y * v.y + v.z * v.z + v.w * v.w;
        ss += __shfl_xor(ss, 1);
        ss += __shfl_xor(ss, 2);
        ss += __shfl_xor(ss, 4);
        ss += __shfl_xor(ss, 8);
        float s = 1.0f / (sqrtf(ss) + EPS);
        s16x4 o;
        o[0] = f2bf(v.x * s);
        o[1] = f2bf(v.y * s);
        o[2] = f2bf(v.z * s);
        o[3] = f2bf(v.w * s);
        *(s16x4*)(Kno + (r << 6) + (c4 ^ ((r & 7) << 3))) = o;
    }

    // ---- V: transpose 64x64 tile via LDS ----
    const float* Vb = V + ((size_t)bh * SEQ + (size_t)nt * 64) * DIM;
    short* Vo = Vt + ((size_t)bh << 17) + (nt << 12);
    __shared__ short lds[DIM * TLDS];
    const int cg = tid & 15;
    const int rr = tid >> 4;
#pragma unroll
    for (int i = 0; i < 4; ++i) {
        int n  = rr + i * 16;
        int d0 = cg * 4;
        float4 v = *(const float4*)(Vb + (size_t)n * DIM + d0);
        lds[(d0 + 0) * TLDS + n] = f2bf(v.x);
        lds[(d0 + 1) * TLDS + n] = f2bf(v.y);
        lds[(d0 + 2) * TLDS + n] = f2bf(v.z);
        lds[(d0 + 3) * TLDS + n] = f2bf(v.w);
    }
    __syncthreads();
#pragma unroll
    for (int i = 0; i < 4; ++i) {
        int d  = rr + i * 16;
        int nl = cg * 4;
        s16x4 o;
        o[0] = lds[d * TLDS + nl + 0];
        o[1] = lds[d * TLDS + nl + 1];
        o[2] = lds[d * TLDS + nl + 2];
        o[3] = lds[d * TLDS + nl + 3];
        *(s16x4*)(Vo + (d << 6) + (nl ^ ((d & 7) << 3))) = o;
    }
}

// ---------------------------------------------------------------------------
// Flash attention. 512 threads = 8 waves, QBLK=256, KVBLK=64.
// Grid 512 = 2 blocks/CU, heavy-first. 4-deep buffered stage, 2 tiles
// ahead, counted vmcnt (4/2/0), ONE s_barrier per tile (wait-before-bar).
//
// mfma_f32_32x32x16_bf16 layouts:
//   A: row = lane&31, k = (lane>>5)*8 + j
//   B: col = lane&31, k = (lane>>5)*8 + j
//   C/D: col = lane&31, row = (reg&3) + 8*(reg>>2) + 4*(lane>>5)
// ---------------------------------------------------------------------------
__global__ __launch_bounds__(512) void attn_fwd(
    const float* __restrict__ Q, const float* __restrict__ scale,
    const short* __restrict__ Kn, const short* __restrict__ Vt,
    float* __restrict__ out)
{
    const int lid = blockIdx.x;                       // 0..511
    const int bh  = (lid & 7) * 8 + ((lid >> 3) & 7); // XCD lid%8 owns bh/8
    const int qb  = 7 - (lid >> 6);                   // heavy q-blocks first
    const int tid = threadIdx.x;
    const int w   = tid >> 6;                         // wave 0..7
    const int l   = tid & 63;
    const int lq  = l & 31;
    const int hi  = l >> 5;

    const short* Kb = Kn + ((size_t)bh << 17);
    const short* Vb = Vt + ((size_t)bh << 17);
    const float  g  = scale[bh & (HEADS - 1)];

    __shared__ __align__(16) short ldsK[4][64 * 64];
    __shared__ __align__(16) short ldsV[4][64 * 64];

    const int toff = tid * 8;   // 512 thr x 8 shorts = full 4096-short tile

    const int wlo  = qb * 256 + w * 32;   // wave's first q-row
    const int whi  = wlo + 31;
    const int qrow = wlo + lq;
    const int nkt  = 4 * qb + 4;

    // ---- prologue: stage tiles 0 and 1 ----
    gload_lds16(Kb + toff,        &ldsK[0][toff]);
    gload_lds16(Vb + toff,        &ldsV[0][toff]);
    gload_lds16(Kb + 4096 + toff, &ldsK[1][toff]);
    gload_lds16(Vb + 4096 + toff, &ldsV[1][toff]);

    // ---- fused Q-norm (overlaps stage latency; its own loads drain once
    //      here, before the steady loop) ----
    const float* Qrow = Q + ((size_t)bh * SEQ + qrow) * DIM;
    float qv[4][8];
    float ss = 0.f;
#pragma unroll
    for (int c = 0; c < 4; ++c) {
        float4 a = *(const float4*)(Qrow + c * 16 + hi * 8);
        float4 b = *(const float4*)(Qrow + c * 16 + hi * 8 + 4);
        qv[c][0] = a.x; qv[c][1] = a.y; qv[c][2] = a.z; qv[c][3] = a.w;
        qv[c][4] = b.x; qv[c][5] = b.y; qv[c][6] = b.z; qv[c][7] = b.w;
#pragma unroll
        for (int jj = 0; jj < 8; ++jj) ss += qv[c][jj] * qv[c][jj];
    }
    ss += __shfl_xor(ss, 32);
    const float sc = g * LOG2E / (sqrtf(ss) + EPS);

    bf16x8 qbf[4];
#pragma unroll
    for (int c = 0; c < 4; ++c) {
        u32x4 wds;
#pragma unroll
        for (int m = 0; m < 4; ++m)
            wds[m] = cvt_pk(qv[c][2 * m] * sc, qv[c][2 * m + 1] * sc);
        qbf[c] = __builtin_bit_cast(bf16x8, wds);
    }

    fx16 oacc[2];
    fx16 lacc;                       // deferred lsum partials (16 lanes-rows)
#pragma unroll
    for (int dt = 0; dt < 2; ++dt)
#pragma unroll
        for (int r = 0; r < 16; ++r) oacc[dt][r] = 0.f;
#pragma unroll
    for (int r = 0; r < 16; ++r) lacc[r] = 0.f;

    int cur = 0;   // kt & 3
    for (int kt = 0; kt < nkt; ++kt) {
        // issue stage(kt+2), wait own stage(kt) landed, THEN one barrier:
        // barrier(kt) retires compute(kt-1) and publishes all waves'
        // stage(kt) slices. Buffer distance 4 protects overwrites.
        if (kt + 2 < nkt) {
            const int nb = (cur + 2) & 3;
            const short* gK = Kb + (size_t)(kt + 2) * 4096;
            const short* gV = Vb + (size_t)(kt + 2) * 4096;
            gload_lds16(gK + toff, &ldsK[nb][toff]);
            gload_lds16(gV + toff, &ldsV[nb][toff]);
            asm volatile("s_waitcnt vmcnt(4)" ::: "memory");
        } else if (kt + 1 < nkt) {
            asm volatile("s_waitcnt vmcnt(2)" ::: "memory");
        } else {
            asm volatile("s_waitcnt vmcnt(0)" ::: "memory");
        }
        __builtin_amdgcn_s_barrier();

        const int k0 = kt * 64;
        if (k0 <= whi) {   // wave-uniform causal skip (barrier outside)
            const short* lk = ldsK[cur];
            const short* lv = ldsV[cur];

            // ---- K frags from LDS (swizzled), S' = K x Q^T ----
            fx16 sacc[2];
#pragma unroll
            for (int t = 0; t < 2; ++t)
#pragma unroll
                for (int r = 0; r < 16; ++r) sacc[t][r] = 0.f;

            bf16x8 kf[2][4];
#pragma unroll
            for (int t = 0; t < 2; ++t)
#pragma unroll
                for (int c = 0; c < 4; ++c) {
                    int r = t * 32 + lq;
                    kf[t][c] = *(const bf16x8*)
                        &lk[(r << 6) + ((c * 16 + hi * 8) ^ ((r & 7) << 3))];
                }
            __builtin_amdgcn_s_setprio(1);
#pragma unroll
            for (int c = 0; c < 4; ++c) {
                sacc[0] = __builtin_amdgcn_mfma_f32_32x32x16_bf16(kf[0][c], qbf[c], sacc[0], 0, 0, 0);
                sacc[1] = __builtin_amdgcn_mfma_f32_32x32x16_bf16(kf[1][c], qbf[c], sacc[1], 0, 0, 0);
            }
            __builtin_amdgcn_s_setprio(0);

            // ---- V frags from LDS (latency hides under softmax) ----
            bf16x8 vf[2][4];
#pragma unroll
            for (int dt = 0; dt < 2; ++dt)
#pragma unroll
                for (int ks = 0; ks < 4; ++ks) {
                    int d = dt * 32 + lq;
                    vf[dt][ks] = *(const bf16x8*)
                        &lv[(d << 6) + ((ks * 16 + hi * 8) ^ ((d & 7) << 3))];
                }

            float pv[32];
#pragma unroll
            for (int t = 0; t < 2; ++t)
#pragma unroll
                for (int r = 0; r < 16; ++r) pv[t * 16 + r] = sacc[t][r];

            // ---- causal mask: only the wave's diagonal tile ----
            if (k0 + 63 > wlo) {
#pragma unroll
                for (int t = 0; t < 2; ++t)
#pragma unroll
                    for (int r = 0; r < 16; ++r) {
                        int key = k0 + 32 * t + (r & 3) + 8 * (r >> 2) + 4 * hi;
                        if (key > qrow) pv[t * 16 + r] = -3.0e38f;
                    }
            }

            // ---- p = exp2(s) (cosine-bounded, no max shift) ----
#pragma unroll
            for (int r = 0; r < 32; ++r)
                pv[r] = __builtin_amdgcn_exp2f(pv[r]);

            // ---- deferred lsum: vector accumulate only (tree in epilogue)
#pragma unroll
            for (int r = 0; r < 16; ++r)
                lacc[r] += pv[r] + pv[r + 16];

            // ---- repack P -> B-fragments via v_permlane32_swap_b32 ----
            u32x4 paw[4];
#pragma unroll
            for (int ks = 0; ks < 4; ++ks) {
                const int t = ks >> 1;
                const int b0 = (ks & 1) * 8;
#pragma unroll
                for (int m = 0; m < 2; ++m) {
                    unsigned a = cvt_pk(pv[t * 16 + b0 + 2 * m], pv[t * 16 + b0 + 2 * m + 1]);
                    unsigned b = cvt_pk(pv[t * 16 + b0 + 2 * m + 4], pv[t * 16 + b0 + 2 * m + 5]);
                    asm("v_permlane32_swap_b32 %0, %1" : "+v"(a), "+v"(b));
                    paw[ks][m]     = a;
                    paw[ks][m + 2] = b;
                }
            }

            // ---- O' += Vt x P ----
            __builtin_amdgcn_s_setprio(1);
#pragma unroll
            for (int dt = 0; dt < 2; ++dt)
#pragma unroll
                for (int ks = 0; ks < 4; ++ks) {
                    bf16x8 pa = __builtin_bit_cast(bf16x8, paw[ks]);
                    oacc[dt] = __builtin_amdgcn_mfma_f32_32x32x16_bf16(vf[dt][ks], pa, oacc[dt], 0, 0, 0);
                }
            __builtin_amdgcn_s_setprio(0);
        }
        cur = (cur + 1) & 3;
    }

    // ---- epilogue: finish lsum reduction, then out[q][d] = O'/lsum ----
    float ts[8];
#pragma unroll
    for (int r = 0; r < 8; ++r) ts[r] = lacc[r] + lacc[r + 8];
#pragma unroll
    for (int r = 0; r < 4; ++r) ts[r] += ts[r + 4];
    float lsum = (ts[0] + ts[1]) + (ts[2] + ts[3]);
    lsum += __shfl_xor(lsum, 32);

    float inv = 1.0f / lsum;
    size_t rb = ((size_t)bh * SEQ + (size_t)qrow) * DIM;
#pragma unroll
    for (int dt = 0; dt < 2; ++dt)
#pragma unroll
        for (int g4 = 0; g4 < 4; ++g4) {
            float4 o4;
            o4.x = oacc[dt][4 * g4 + 0] * inv;
            o4.y = oacc[dt][4 * g4 + 1] * inv;
            o4.z = oacc[dt][4 * g4 + 2] * inv;
            o4.w = oacc[dt][4 * g4 + 3] * inv;
            *(float4*)(out + rb + dt * 32 + 8 * g4 + 4 * hi) = o4;
        }
}

// ---------------------------------------------------------------------------
extern "C" void kernel_launch(void* const* d_in, const int* in_sizes, int n_in,
                              void* d_out, int out_size, void* d_ws, size_t ws_size,
                              hipStream_t stream)
{
    const float* Q  = (const float*)d_in[0];
    const float* K  = (const float*)d_in[1];
    const float* V  = (const float*)d_in[2];
    const float* qs = (const float*)d_in[3];
    float* out = (float*)d_out;

    const size_t nElem = (size_t)BATCH * HEADS * SEQ * DIM;
    short* Kn = (short*)d_ws;
    short* Vt = Kn + nElem;

    {
        dim3 grid(SEQ / 64, BATCH * HEADS);
        prep_kv<<<grid, 256, 0, stream>>>(K, V, Kn, Vt);
    }
    {
        // 512 blocks = 2/CU: XCD lid%8 owns bh chunk; 8 q-blocks per bh
        attn_fwd<<<(SEQ / 256) * BATCH * HEADS, 512, 0, stream>>>(Q, qs, Kn, Vt, out);
    }
}